// Round 7
// baseline (320.389 us; speedup 1.0000x reference)
//
#include <hip/hip_runtime.h>
#include <hip/hip_bf16.h>
#include <math.h>

#define BB 512
#define DD 128
#define CC 100000

#define BLK_M 64
#define BLK_N 64
#define LDB 136                 // bf16 units; 272B row stride
#define LDT 68                  // f32 units; transpose buffer row stride

__device__ __constant__ const float COS_M  =  0.87758256189037271612f;  // cos(0.5)
__device__ __constant__ const float SIN_M  =  0.47942553860420300538f;  // sin(0.5)
__device__ __constant__ const float THRESH = -0.87758256189037271612f;  // cos(pi-0.5)
__device__ __constant__ const float MMc    =  0.23971276930210150269f;  // sin(0.5)*0.5
#define SCALE_F 64.0f
#define ALPHA_F 1.2f

typedef __attribute__((ext_vector_type(8))) short short8;
typedef __attribute__((ext_vector_type(4))) float float4v;

__device__ inline float waveReduceSum(float v) {
    #pragma unroll
    for (int off = 32; off > 0; off >>= 1)
        v += __shfl_xor(v, off, 64);
    return v;
}

// --- K1: fused feats-normalize (-> bf16 exb) + per-row a_lb (full fp32) ---
__global__ void k_prep(const float* __restrict__ feats, const float* __restrict__ w,
                       const int* __restrict__ labels,
                       __hip_bfloat16* __restrict__ exb, float* __restrict__ alb) {
    int b = blockIdx.x;
    int lane = threadIdx.x;          // 64 threads, 2 floats each
    int lab = labels[b];
    float2 f = ((const float2*)(feats + b * DD))[lane];
    float2 g = ((const float2*)(w + (size_t)lab * DD))[lane];
    float nf  = waveReduceSum(f.x * f.x + f.y * f.y);
    float dot = waveReduceSum(f.x * g.x + f.y * g.y);
    float nw  = waveReduceSum(g.x * g.x + g.y * g.y);
    float rn = rsqrtf(nf);
    __hip_bfloat162 o;
    o.x = __float2bfloat16(f.x * rn);
    o.y = __float2bfloat16(f.y * rn);
    ((__hip_bfloat162*)(exb + b * DD))[lane] = o;
    if (lane == 0) {
        float c = dot * rsqrtf(nf * nw);
        float a;
        if (c > THRESH) {
            float cc = fminf(fmaxf(c, -1.0f), 1.0f);
            a = cc * COS_M - SIN_M * sqrtf(fmaxf(0.0f, 1.0f - cc * cc));  // cos(acos+M)
        } else {
            a = c - MMc;
        }
        alb[b] = a;
    }
}

// --- K2: paced column-tile kernel, NO LDS-A staging ---
// 1563 blocks, 256 threads (4 waves), 4 blocks/CU (LDS 34,816 B).
// vs 254.6us baseline: the global->VGPR->LDS->VGPR A-staging chain is gone.
// A-fragments are read straight from L1/L2-resident exb (131 KB) inside the
// swapped MFMA loop (layout verified in round 6: D[class][batch], col=lane&15
// -> batch row, row=lquad*4+e -> class). Store path kept IDENTICAL to the
// baseline: per-wave b128 writes into the padded Tr buffer, row-major read,
// full-line 256B nontemporal stores. 2 barriers/phase (was 4).
__global__ __launch_bounds__(256, 4)
void k_main(const __hip_bfloat16* __restrict__ exb,
            const float* __restrict__ w,
            const float* __restrict__ alb,
            const int* __restrict__ labels,
            float* __restrict__ out) {
    __shared__ __align__(16) __hip_bfloat16 Bs[BLK_N][LDB];    // 17408 B
    __shared__ __align__(16) float Tr[BLK_M][LDT];             // 17408 B

    int tid = threadIdx.x;
    int c0 = blockIdx.x * BLK_N;

    // ---- normalize BLK_N weight rows into Bs (4 threads per row) ----
    {
        int r = tid >> 2;            // 0..63
        int h = tid & 3;             // quarter-row: 32 floats
        int c = c0 + r;
        float4 buf[8];
        float ss = 0.f;
        if (c < CC) {
            const float4* src = (const float4*)(w + (size_t)c * DD + h * 32);
            #pragma unroll
            for (int j = 0; j < 8; j++) {
                buf[j] = src[j];
                ss += buf[j].x * buf[j].x + buf[j].y * buf[j].y
                    + buf[j].z * buf[j].z + buf[j].w * buf[j].w;
            }
        } else {
            #pragma unroll
            for (int j = 0; j < 8; j++) buf[j] = make_float4(0.f, 0.f, 0.f, 0.f);
        }
        float tot = ss + __shfl_xor(ss, 1, 64);
        tot += __shfl_xor(tot, 2, 64);           // lanes 4r..4r+3 are wave-adjacent
        float rn = (c < CC) ? rsqrtf(tot) : 0.f;
        #pragma unroll
        for (int j = 0; j < 4; j++) {
            __hip_bfloat16 tmp[8];
            float4 a = buf[2 * j], b2 = buf[2 * j + 1];
            tmp[0] = __float2bfloat16(a.x * rn);
            tmp[1] = __float2bfloat16(a.y * rn);
            tmp[2] = __float2bfloat16(a.z * rn);
            tmp[3] = __float2bfloat16(a.w * rn);
            tmp[4] = __float2bfloat16(b2.x * rn);
            tmp[5] = __float2bfloat16(b2.y * rn);
            tmp[6] = __float2bfloat16(b2.z * rn);
            tmp[7] = __float2bfloat16(b2.w * rn);
            *(uint4*)(&Bs[r][h * 32 + j * 8]) = *(const uint4*)tmp;
        }
    }
    __syncthreads();   // Bs visible to all waves

    int wave = tid >> 6;
    int lane = tid & 63;
    int lrow = lane & 15;
    int lquad = lane >> 4;

    // ---- hoist this wave's class fragments (loop-invariant): 16 VGPRs ----
    short8 cf[4];
    #pragma unroll
    for (int ks = 0; ks < 4; ks++)
        cf[ks] = *(const short8*)(&Bs[wave * 16 + lrow][ks * 32 + lquad * 8]);

    for (int rb = 0; rb < BB / BLK_M; rb++) {
        // ---- swapped MFMA, A-fragments straight from L1/L2-hot exb ----
        // acc[bt][e] = cos(batch rb*64 + bt*16 + lrow, class c0 + wave*16 + lquad*4 + e)
        const __hip_bfloat16* abase = exb + (size_t)rb * BLK_M * DD;
        float4v acc[4];
        #pragma unroll
        for (int bt = 0; bt < 4; bt++) acc[bt] = (float4v)(0.0f);
        #pragma unroll
        for (int ks = 0; ks < 4; ks++) {
            #pragma unroll
            for (int bt = 0; bt < 4; bt++) {
                short8 af = *(const short8*)(abase + (bt * 16 + lrow) * DD + ks * 32 + lquad * 8);
                acc[bt] = __builtin_amdgcn_mfma_f32_16x16x32_bf16(cf[ks], af, acc[bt], 0, 0, 0);
            }
        }

        __syncthreads();   // epilogue(rb-1) Tr reads done -> Tr reusable
                           // (MFMA above overlapped other waves' epilogue)

        // ---- b128 transpose writes: Tr[batch_local][class_local] ----
        #pragma unroll
        for (int bt = 0; bt < 4; bt++)
            *(float4v*)(&Tr[bt * 16 + lrow][wave * 16 + lquad * 4]) = acc[bt];

        __syncthreads();   // tile transposed

        // ---- row-major epilogue + full-line 256B nontemporal stores ----
        // out = SCALE*( onehot*a + (1-onehot)*(rw*cos + rw - 1) ), rw = ALPHA*exp(-(cos-a)^2/2)
        #pragma unroll
        for (int it = 0; it < 4; it++) {
            int flat = it * 256 + tid;          // 0..1023
            int r  = flat >> 4;                 // tile row 0..63
            int c4 = flat & 15;                 // float4 index within row
            int b = rb * BLK_M + r;
            int cbase = c0 + c4 * 4;
            if (cbase < CC) {                   // CC%4==0, c0%64==0 -> whole float4 valid
                float a = alb[b];
                int lab = labels[b];
                float4v v = *(const float4v*)(&Tr[r][c4 * 4]);
                float4v res;
                #pragma unroll
                for (int e = 0; e < 4; e++) {
                    float cosv = v[e];
                    float d = cosv - a;
                    float rw = ALPHA_F * __expf(-0.5f * d * d);
                    res[e] = (cbase + e == lab) ? SCALE_F * a
                                                : SCALE_F * (rw * cosv + rw - 1.0f);
                }
                __builtin_nontemporal_store(res, (float4v*)(out + (size_t)b * CC + cbase));
            }
        }
    }
}

extern "C" void kernel_launch(void* const* d_in, const int* in_sizes, int n_in,
                              void* d_out, int out_size, void* d_ws, size_t ws_size,
                              hipStream_t stream) {
    const float* feats  = (const float*)d_in[0];
    const int*   labels = (const int*)d_in[1];
    const float* weight = (const float*)d_in[2];
    float* out = (float*)d_out;

    char* ws = (char*)d_ws;
    __hip_bfloat16* exb = (__hip_bfloat16*)ws;            // 512*128*2 = 131072 B
    float* alb = (float*)(ws + 131072);                   // 2048 B

    hipLaunchKernelGGL(k_prep, dim3(BB), dim3(64), 0, stream,
                       feats, weight, labels, exb, alb);

    dim3 grid((CC + BLK_N - 1) / BLK_N);                  // 1563 column tiles
    hipLaunchKernelGGL(k_main, grid, dim3(256), 0, stream,
                       exb, weight, alb, labels, out);
}

// Round 8
// 272.642 us; speedup vs baseline: 1.1751x; 1.1751x over previous
//
#include <hip/hip_runtime.h>
#include <hip/hip_bf16.h>
#include <math.h>

#define BB 512
#define DD 128
#define CC 100000

#define CLS_PB 256              // classes per block
#define ROWS_PG 256             // rows per block (grid.y = 2)
#define LDB 136                 // bf16 units; staging pad
#define LDT 260                 // f32 units; 256-col transpose row + pad

__device__ __constant__ const float COS_M  =  0.87758256189037271612f;  // cos(0.5)
__device__ __constant__ const float SIN_M  =  0.47942553860420300538f;  // sin(0.5)
__device__ __constant__ const float THRESH = -0.87758256189037271612f;  // cos(pi-0.5)
__device__ __constant__ const float MMc    =  0.23971276930210150269f;  // sin(0.5)*0.5
#define SCALE_F 64.0f
#define ALPHA_F 1.2f

typedef __attribute__((ext_vector_type(8))) short short8;
typedef __attribute__((ext_vector_type(4))) float float4v;

__device__ inline float waveReduceSum(float v) {
    #pragma unroll
    for (int off = 32; off > 0; off >>= 1)
        v += __shfl_xor(v, off, 64);
    return v;
}

// --- K1: fused feats-normalize (-> bf16 exb) + per-row a_lb (full fp32) ---
__global__ void k_prep(const float* __restrict__ feats, const float* __restrict__ w,
                       const int* __restrict__ labels,
                       __hip_bfloat16* __restrict__ exb, float* __restrict__ alb) {
    int b = blockIdx.x;
    int lane = threadIdx.x;          // 64 threads, 2 floats each
    int lab = labels[b];
    float2 f = ((const float2*)(feats + b * DD))[lane];
    float2 g = ((const float2*)(w + (size_t)lab * DD))[lane];
    float nf  = waveReduceSum(f.x * f.x + f.y * f.y);
    float dot = waveReduceSum(f.x * g.x + f.y * g.y);
    float nw  = waveReduceSum(g.x * g.x + g.y * g.y);
    float rn = rsqrtf(nf);
    __hip_bfloat162 o;
    o.x = __float2bfloat16(f.x * rn);
    o.y = __float2bfloat16(f.y * rn);
    ((__hip_bfloat162*)(exb + b * DD))[lane] = o;
    if (lane == 0) {
        float c = dot * rsqrtf(nf * nw);
        float a;
        if (c > THRESH) {
            float cc = fminf(fmaxf(c, -1.0f), 1.0f);
            a = cc * COS_M - SIN_M * sqrtf(fmaxf(0.0f, 1.0f - cc * cc));  // cos(acos+M)
        } else {
            a = c - MMc;
        }
        alb[b] = a;
    }
}

// --- K2: 1KB-burst store kernel. Grid (391, 2), 256 threads (4 waves). ---
// Round-7 PMC: stores are DRAM page-activate bound (256B segments -> 26% page
// utilization -> 1.71 TB/s). Fix: each wave stores ONE CONTIGUOUS 1KB row
// segment per instruction (64 lanes x 16B).
// Block = 256 classes x 256 rows.
//   Prologue: 4 rounds x {normalize 64 weight rows -> LDS stage; owning wave
//   reads its cf[4][4] class fragments (64 VGPRs)}.
//   Phase loop (16 x 16 rows): batch frags from L2-hot exb; swapped MFMA
//   D[class][batch] (layout HW-verified r6/r7); write 16x256 f32 tile into
//   double-buffered padded Tr (ONE barrier/phase); epilogue: wave w handles
//   row it*4+w, lane l reads Tr[r][4l] and NT-stores out[b][c0+4l] -> 1KB
//   bursts at 4x the page utilization.
// LDS 50,688 B -> 3 blocks/CU; 782 blocks = 1.02 residency rounds.
__global__ __launch_bounds__(256, 3)
void k_main(const __hip_bfloat16* __restrict__ exb,
            const float* __restrict__ w,
            const float* __restrict__ alb,
            const int* __restrict__ labels,
            float* __restrict__ out) {
    __shared__ __align__(16) __hip_bfloat16 Bstage[64][LDB];   // 17,408 B
    __shared__ __align__(16) float Tr[2][16][LDT];             // 33,280 B

    int tid = threadIdx.x;
    int wave = tid >> 6;
    int lane = tid & 63;
    int lrow = lane & 15;
    int lquad = lane >> 4;
    int c0 = blockIdx.x * CLS_PB;
    int ry = blockIdx.y * ROWS_PG;

    // ---- prologue: 4 rounds of normalize-and-grab ----
    short8 cf[4][4];                 // [strip s][ks]: classes c0+wave*64+s*16+lrow
    #pragma unroll
    for (int rnd = 0; rnd < 4; rnd++) {
        {
            int r = tid >> 2;        // 0..63
            int h = tid & 3;         // quarter-row: 32 floats
            int c = c0 + rnd * 64 + r;
            float4 buf[8];
            float ss = 0.f;
            if (c < CC) {
                const float4* src = (const float4*)(w + (size_t)c * DD + h * 32);
                #pragma unroll
                for (int j = 0; j < 8; j++) {
                    buf[j] = src[j];
                    ss += buf[j].x * buf[j].x + buf[j].y * buf[j].y
                        + buf[j].z * buf[j].z + buf[j].w * buf[j].w;
                }
            } else {
                #pragma unroll
                for (int j = 0; j < 8; j++) buf[j] = make_float4(0.f, 0.f, 0.f, 0.f);
            }
            float tot = ss + __shfl_xor(ss, 1, 64);
            tot += __shfl_xor(tot, 2, 64);       // lanes 4r..4r+3 are wave-adjacent
            float rn = (c < CC) ? rsqrtf(tot) : 0.f;
            #pragma unroll
            for (int j = 0; j < 4; j++) {
                __hip_bfloat16 tmp[8];
                float4 a = buf[2 * j], b2 = buf[2 * j + 1];
                tmp[0] = __float2bfloat16(a.x * rn);
                tmp[1] = __float2bfloat16(a.y * rn);
                tmp[2] = __float2bfloat16(a.z * rn);
                tmp[3] = __float2bfloat16(a.w * rn);
                tmp[4] = __float2bfloat16(b2.x * rn);
                tmp[5] = __float2bfloat16(b2.y * rn);
                tmp[6] = __float2bfloat16(b2.z * rn);
                tmp[7] = __float2bfloat16(b2.w * rn);
                *(uint4*)(&Bstage[r][h * 32 + j * 8]) = *(const uint4*)tmp;
            }
        }
        __syncthreads();             // stage visible
        if (wave == rnd) {           // wave-uniform branch
            #pragma unroll
            for (int s = 0; s < 4; s++)
                #pragma unroll
                for (int ks = 0; ks < 4; ks++)
                    cf[s][ks] = *(const short8*)(&Bstage[s * 16 + lrow][ks * 32 + lquad * 8]);
        }
        __syncthreads();             // grab done before next overwrite
    }

    // ---- phase loop: 16 phases of 16 batch rows ----
    for (int rb = 0; rb < ROWS_PG / 16; rb++) {
        int b0 = ry + rb * 16;

        // batch fragments from L2-hot exb (identical addrs across waves -> L1 broadcast)
        const __hip_bfloat16* abase = exb + (size_t)b0 * DD;
        short8 af[4];
        #pragma unroll
        for (int ks = 0; ks < 4; ks++)
            af[ks] = *(const short8*)(abase + lrow * DD + ks * 32 + lquad * 8);

        float4v acc[4];
        #pragma unroll
        for (int s = 0; s < 4; s++) acc[s] = (float4v)(0.0f);

        #pragma unroll
        for (int ks = 0; ks < 4; ks++)
            #pragma unroll
            for (int s = 0; s < 4; s++)
                acc[s] = __builtin_amdgcn_mfma_f32_16x16x32_bf16(cf[s][ks], af[ks], acc[s], 0, 0, 0);

        // ---- transpose into double-buffered Tr (write p; prior phase read p^1) ----
        // acc[s][e]: batch row lrow, class-local wave*64 + s*16 + lquad*4 + e
        int p = rb & 1;
        #pragma unroll
        for (int s = 0; s < 4; s++)
            *(float4v*)(&Tr[p][lrow][wave * 64 + s * 16 + lquad * 4]) = acc[s];

        __syncthreads();             // the ONLY barrier per phase

        // ---- epilogue: wave-uniform row, 1KB contiguous NT burst per wave ----
        // out = SCALE*( onehot*a + (1-onehot)*(rw*cos + rw - 1) ), rw = ALPHA*exp(-(cos-a)^2/2)
        int cl = c0 + 4 * lane;      // this lane's 4 output classes
        bool cok = cl < CC;          // CC%4==0 -> whole float4 valid or invalid
        #pragma unroll
        for (int it = 0; it < 4; it++) {
            int r = it * 4 + wave;   // wave-uniform local row
            int b = b0 + r;
            float a = alb[b];
            int lab = labels[b];
            float4v v = *(const float4v*)(&Tr[p][r][4 * lane]);
            if (cok) {
                float4v res;
                #pragma unroll
                for (int e = 0; e < 4; e++) {
                    float cosv = v[e];
                    float d = cosv - a;
                    float rw = ALPHA_F * __expf(-0.5f * d * d);
                    res[e] = (cl + e == lab) ? SCALE_F * a
                                             : SCALE_F * (rw * cosv + rw - 1.0f);
                }
                __builtin_nontemporal_store(res, (float4v*)(out + (size_t)b * CC + cl));
            }
        }
    }
}

extern "C" void kernel_launch(void* const* d_in, const int* in_sizes, int n_in,
                              void* d_out, int out_size, void* d_ws, size_t ws_size,
                              hipStream_t stream) {
    const float* feats  = (const float*)d_in[0];
    const int*   labels = (const int*)d_in[1];
    const float* weight = (const float*)d_in[2];
    float* out = (float*)d_out;

    char* ws = (char*)d_ws;
    __hip_bfloat16* exb = (__hip_bfloat16*)ws;            // 512*128*2 = 131072 B
    float* alb = (float*)(ws + 131072);                   // 2048 B

    hipLaunchKernelGGL(k_prep, dim3(BB), dim3(64), 0, stream,
                       feats, weight, labels, exb, alb);

    dim3 grid((CC + CLS_PB - 1) / CLS_PB, BB / ROWS_PG);  // (391, 2)
    hipLaunchKernelGGL(k_main, grid, dim3(256), 0, stream,
                       exb, weight, alb, labels, out);
}

// Round 9
// 264.607 us; speedup vs baseline: 1.2108x; 1.0304x over previous
//
#include <hip/hip_runtime.h>
#include <hip/hip_bf16.h>
#include <math.h>

#define BB 512
#define DD 128
#define CC 100000

#define BLK_M 64
#define BLK_N 64
#define LDA 136                 // bf16 units; 272B row stride -> balanced b128 MFMA reads
#define LDB 136
#define LDT 68                  // f32 units for the transpose view of the A buffer

// XCD-chunked bijective swizzle (m204): nwg=1563, 8 XCDs
#define NWG 1563
#define NXCD 8
#define SWZ_Q (NWG / NXCD)      // 195
#define SWZ_R (NWG % NXCD)      // 3

__device__ __constant__ const float COS_M  =  0.87758256189037271612f;  // cos(0.5)
__device__ __constant__ const float SIN_M  =  0.47942553860420300538f;  // sin(0.5)
__device__ __constant__ const float THRESH = -0.87758256189037271612f;  // cos(pi-0.5)
__device__ __constant__ const float MMc    =  0.23971276930210150269f;  // sin(0.5)*0.5
#define SCALE_F 64.0f
#define ALPHA_F 1.2f

typedef __attribute__((ext_vector_type(8))) short short8;
typedef __attribute__((ext_vector_type(4))) float float4v;

__device__ inline float waveReduceSum(float v) {
    #pragma unroll
    for (int off = 32; off > 0; off >>= 1)
        v += __shfl_xor(v, off, 64);
    return v;
}

// --- K1: fused feats-normalize (-> bf16 exb) + per-row a_lb (full fp32) ---
__global__ void k_prep(const float* __restrict__ feats, const float* __restrict__ w,
                       const int* __restrict__ labels,
                       __hip_bfloat16* __restrict__ exb, float* __restrict__ alb) {
    int b = blockIdx.x;
    int lane = threadIdx.x;          // 64 threads, 2 floats each
    int lab = labels[b];
    float2 f = ((const float2*)(feats + b * DD))[lane];
    float2 g = ((const float2*)(w + (size_t)lab * DD))[lane];
    float nf  = waveReduceSum(f.x * f.x + f.y * f.y);
    float dot = waveReduceSum(f.x * g.x + f.y * g.y);
    float nw  = waveReduceSum(g.x * g.x + g.y * g.y);
    float rn = rsqrtf(nf);
    __hip_bfloat162 o;
    o.x = __float2bfloat16(f.x * rn);
    o.y = __float2bfloat16(f.y * rn);
    ((__hip_bfloat162*)(exb + b * DD))[lane] = o;
    if (lane == 0) {
        float c = dot * rsqrtf(nf * nw);
        float a;
        if (c > THRESH) {
            float cc = fminf(fmaxf(c, -1.0f), 1.0f);
            a = cc * COS_M - SIN_M * sqrtf(fmaxf(0.0f, 1.0f - cc * cc));  // cos(acos+M)
        } else {
            a = c - MMc;
        }
        alb[b] = a;
    }
}

// --- K2: column-tile kernel (verified baseline structure + r5 XCD swizzle) ---
// 1563 blocks, 256 threads (4 waves), 4 blocks/CU (LDS 34,816 B).
// ONE change vs the 255.4us r5 kernel: the epilogue stores are PLAIN CACHED
// instead of nontemporal. r7 PMC showed NT stores reach DRAM as isolated
// 256B segments at 400KB stride -> ~26% page utilization -> 1.52 TB/s write
// rate while every pipe idles. Cached stores land in L2 first; with the XCD
// swizzle the ~128 co-resident blocks per XCD hold ADJACENT 64-col segments
// of the SAME 64-row band (barrier pacing keeps them in the same rb phase),
// so each output row accumulates ~32KB contiguous in that XCD's L2 and
// evicts to DRAM in page-friendly runs (the mechanism behind the 6.5 TB/s
// fill). Each 128B line is fully covered by one store instruction's lanes
// -> no read-for-ownership (FETCH stays flat; verified r6/r7).
__global__ __launch_bounds__(256, 4)
void k_main(const __hip_bfloat16* __restrict__ exb,
            const float* __restrict__ w,
            const float* __restrict__ alb,
            const int* __restrict__ labels,
            float* __restrict__ out) {
    __shared__ __align__(16) char smemA[BLK_M * LDA * 2];      // 17408 B: bf16 A-tile, then f32 transpose
    __shared__ __align__(16) __hip_bfloat16 Bs[BLK_N][LDB];    // 17408 B

    __hip_bfloat16 (*As)[LDA] = (__hip_bfloat16(*)[LDA])smemA;
    float (*Tr)[LDT] = (float(*)[LDT])smemA;

    int tid = threadIdx.x;

    // ---- bijective XCD-chunked swizzle (HW round-robins orig%8 across XCDs) ----
    int orig = blockIdx.x;
    int xcd = orig & (NXCD - 1);
    int idx = orig >> 3;
    int nb = (xcd < SWZ_R) ? xcd * (SWZ_Q + 1) + idx
                           : SWZ_R * (SWZ_Q + 1) + (xcd - SWZ_R) * SWZ_Q + idx;
    int c0 = nb * BLK_N;

    // ---- normalize BLK_N weight rows into Bs (4 threads per row) ----
    {
        int r = tid >> 2;            // 0..63
        int h = tid & 3;             // quarter-row: 32 floats
        int c = c0 + r;
        float4 buf[8];
        float ss = 0.f;
        if (c < CC) {
            const float4* src = (const float4*)(w + (size_t)c * DD + h * 32);
            #pragma unroll
            for (int j = 0; j < 8; j++) {
                buf[j] = src[j];
                ss += buf[j].x * buf[j].x + buf[j].y * buf[j].y
                    + buf[j].z * buf[j].z + buf[j].w * buf[j].w;
            }
        } else {
            #pragma unroll
            for (int j = 0; j < 8; j++) buf[j] = make_float4(0.f, 0.f, 0.f, 0.f);
        }
        float tot = ss + __shfl_xor(ss, 1, 64);
        tot += __shfl_xor(tot, 2, 64);           // lanes 4r..4r+3 are wave-adjacent
        float rn = (c < CC) ? rsqrtf(tot) : 0.f;
        #pragma unroll
        for (int j = 0; j < 4; j++) {
            __hip_bfloat16 tmp[8];
            float4 a = buf[2 * j], b2 = buf[2 * j + 1];
            tmp[0] = __float2bfloat16(a.x * rn);
            tmp[1] = __float2bfloat16(a.y * rn);
            tmp[2] = __float2bfloat16(a.z * rn);
            tmp[3] = __float2bfloat16(a.w * rn);
            tmp[4] = __float2bfloat16(b2.x * rn);
            tmp[5] = __float2bfloat16(b2.y * rn);
            tmp[6] = __float2bfloat16(b2.z * rn);
            tmp[7] = __float2bfloat16(b2.w * rn);
            *(uint4*)(&Bs[r][h * 32 + j * 8]) = *(const uint4*)tmp;
        }
    }

    int wave = tid >> 6;
    int lane = tid & 63;
    int lrow = lane & 15;
    int lquad = lane >> 4;

    for (int rb = 0; rb < BB / BLK_M; rb++) {
        __syncthreads();   // prev-iter Tr reads done (and normalize done, iter 0)

        // ---- stage A tile (64x128 bf16 = 1024 uint4, 4 per thread) ----
        {
            const uint4* src = (const uint4*)(exb + (size_t)rb * BLK_M * DD);
            #pragma unroll
            for (int j = 0; j < 4; j++) {
                int i = tid + j * 256;
                int r = i >> 4, kc = i & 15;
                *(uint4*)(&As[r][kc * 8]) = src[i];
            }
        }
        __syncthreads();   // A staged, Bs visible

        float4v acc[4];
        #pragma unroll
        for (int i = 0; i < 4; i++) acc[i] = (float4v)(0.0f);

        #pragma unroll
        for (int ks = 0; ks < 4; ks++) {
            int k0 = ks * 32 + lquad * 8;
            short8 bf = *(const short8*)(&Bs[wave * 16 + lrow][k0]);
            #pragma unroll
            for (int mt = 0; mt < 4; mt++) {
                short8 af = *(const short8*)(&As[mt * 16 + lrow][k0]);
                acc[mt] = __builtin_amdgcn_mfma_f32_16x16x32_bf16(af, bf, acc[mt], 0, 0, 0);
            }
        }
        __syncthreads();   // all As reads done; A buffer now reusable as Tr

        // ---- write f32 tile into transpose buffer ----
        // value (mt,reg): row = mt*16 + lquad*4 + reg, col = wave*16 + lrow
        #pragma unroll
        for (int mt = 0; mt < 4; mt++)
            #pragma unroll
            for (int reg = 0; reg < 4; reg++)
                Tr[mt * 16 + lquad * 4 + reg][wave * 16 + lrow] = acc[mt][reg];
        __syncthreads();   // tile transposed

        // ---- row-major epilogue + full-line CACHED stores ----
        // out = SCALE*( onehot*a + (1-onehot)*(rw*cos + rw - 1) ), rw = ALPHA*exp(-(cos-a)^2/2)
        #pragma unroll
        for (int it = 0; it < 4; it++) {
            int flat = it * 256 + tid;          // 0..1023
            int r  = flat >> 4;                 // tile row 0..63
            int c4 = flat & 15;                 // float4 index within row
            int b = rb * BLK_M + r;
            int cbase = c0 + c4 * 4;
            if (cbase < CC) {                   // CC%4==0, c0%64==0 -> whole float4 valid
                float a = alb[b];
                int lab = labels[b];
                float4v v = *(const float4v*)(&Tr[r][c4 * 4]);
                float4v res;
                #pragma unroll
                for (int e = 0; e < 4; e++) {
                    float cosv = v[e];
                    float d = cosv - a;
                    float rw = ALPHA_F * __expf(-0.5f * d * d);
                    res[e] = (cbase + e == lab) ? SCALE_F * a
                                                : SCALE_F * (rw * cosv + rw - 1.0f);
                }
                *(float4v*)(out + (size_t)b * CC + cbase) = res;   // cached: L2 merges adjacent blocks' segments
            }
        }
    }
}

extern "C" void kernel_launch(void* const* d_in, const int* in_sizes, int n_in,
                              void* d_out, int out_size, void* d_ws, size_t ws_size,
                              hipStream_t stream) {
    const float* feats  = (const float*)d_in[0];
    const int*   labels = (const int*)d_in[1];
    const float* weight = (const float*)d_in[2];
    float* out = (float*)d_out;

    char* ws = (char*)d_ws;
    __hip_bfloat16* exb = (__hip_bfloat16*)ws;            // 512*128*2 = 131072 B
    float* alb = (float*)(ws + 131072);                   // 2048 B

    hipLaunchKernelGGL(k_prep, dim3(BB), dim3(64), 0, stream,
                       feats, weight, labels, exb, alb);

    dim3 grid((CC + BLK_N - 1) / BLK_N);                  // 1563 column tiles
    hipLaunchKernelGGL(k_main, grid, dim3(256), 0, stream,
                       exb, weight, alb, labels, out);
}